// Round 8
// baseline (689.852 us; speedup 1.0000x reference)
//
#include <hip/hip_runtime.h>

// 3-layer GCN, pull-mode CSR gather, aggregate-before-transform, prescaled features.
// CSR build = 2-pass LDS-staged multisplit counting sort (bucket = dst>>8).
// xw transform (R8): LDS-staged GEMM-style — block owns 64 contiguous nodes,
// stages the (contiguous!) 64xK tile via coalesced float4 copy, computes from
// LDS broadcast reads with W K-chunks in registers. R7 lesson: broadcast GLOBAL
// row loads deliver 16 unique B/instr and serialize on L2 latency (VALUBusy 15%).
// agg: float4 lanes (C/4 lanes per node) -> 4x rows in flight per gather instr.

#define TPB 256
#define BSH 8                 // 256 nodes per bucket
#define NBMAX 512             // LDS histogram slots (nb = 391 actual)
#define IPT 32                // edges per thread -> 8192 edges per block

static inline int cdiv(long long a, int b) { return (int)((a + b - 1) / b); }

__global__ __launch_bounds__(TPB) void bhist_zero(int* __restrict__ bhist, int m) {
    int i = blockIdx.x * TPB + threadIdx.x;
    if (i < m) bhist[i] = 0;
}

__global__ __launch_bounds__(TPB) void ms_hist(const int* __restrict__ dst,
                                               int* __restrict__ bhist, int e) {
    __shared__ int h[NBMAX];
    int tid = threadIdx.x;
    h[tid] = 0; h[tid + TPB] = 0;
    __syncthreads();
    int base = blockIdx.x * (TPB * IPT);
#pragma unroll 8
    for (int k = 0; k < IPT; ++k) {
        int i = base + k * TPB + tid;
        if (i < e) atomicAdd(&h[dst[i] >> BSH], 1);
    }
    __syncthreads();
    int v0 = h[tid], v1 = h[tid + TPB];
    if (v0) atomicAdd(&bhist[tid], v0);
    if (v1) atomicAdd(&bhist[tid + TPB], v1);
}

// single-block exclusive scan of bhist[NBMAX] -> boff/bcur[0..NBMAX]
__global__ __launch_bounds__(TPB) void bscan(const int* __restrict__ bhist,
                                             int* __restrict__ boff,
                                             int* __restrict__ bcur) {
    __shared__ int lds[TPB];
    int tid = threadIdx.x;
    int a = bhist[2 * tid], b = bhist[2 * tid + 1];
    int s = a + b;
    lds[tid] = s;
    __syncthreads();
    for (int off = 1; off < TPB; off <<= 1) {
        int x = (tid >= off) ? lds[tid - off] : 0;
        __syncthreads();
        lds[tid] += x;
        __syncthreads();
    }
    int excl = lds[tid] - s;
    boff[2 * tid] = excl;       bcur[2 * tid] = excl;
    boff[2 * tid + 1] = excl + a; bcur[2 * tid + 1] = excl + a;
    if (tid == TPB - 1) { boff[NBMAX] = lds[TPB - 1]; bcur[NBMAX] = lds[TPB - 1]; }
}

__global__ __launch_bounds__(TPB) void ms_scatter(const int* __restrict__ src,
                                                  const int* __restrict__ dst,
                                                  int* __restrict__ bcur,
                                                  int2* __restrict__ pairs, int e) {
    __shared__ int h[NBMAX];
    __shared__ int sbase[NBMAX];
    int tid = threadIdx.x;
    h[tid] = 0; h[tid + TPB] = 0;
    __syncthreads();
    int base = blockIdx.x * (TPB * IPT);
#pragma unroll 8
    for (int k = 0; k < IPT; ++k) {
        int i = base + k * TPB + tid;
        if (i < e) atomicAdd(&h[dst[i] >> BSH], 1);
    }
    __syncthreads();
    int v0 = h[tid], v1 = h[tid + TPB];
    if (v0) sbase[tid] = atomicAdd(&bcur[tid], v0);
    if (v1) sbase[tid + TPB] = atomicAdd(&bcur[tid + TPB], v1);
    __syncthreads();
#pragma unroll 8
    for (int k = 0; k < IPT; ++k) {
        int i = base + k * TPB + tid;
        if (i < e) {
            int s = src[i], d = dst[i];
            int pos = atomicAdd(&sbase[d >> BSH], 1);
            pairs[pos] = make_int2(s, d);
        }
    }
}

// one WG per bucket: histogram -> scan -> rowptr/dinv -> csr placement
__global__ __launch_bounds__(TPB) void build_csr(const int2* __restrict__ pairs,
                                                 const int* __restrict__ boff,
                                                 int* __restrict__ rowptr,
                                                 float* __restrict__ dinv,
                                                 int* __restrict__ csr, int n, int e) {
    int b = blockIdx.x;
    int p0 = boff[b], p1 = boff[b + 1];
    __shared__ int scnt[TPB];
    __shared__ int sbase[TPB];
    __shared__ int lds[TPB];
    int tid = threadIdx.x;
    scnt[tid] = 0;
    __syncthreads();
    for (int j = p0 + tid; j < p1; j += TPB)
        atomicAdd(&scnt[pairs[j].y & (TPB - 1)], 1);
    __syncthreads();
    int c = scnt[tid];
    lds[tid] = c;
    __syncthreads();
    for (int off = 1; off < TPB; off <<= 1) {
        int x = (tid >= off) ? lds[tid - off] : 0;
        __syncthreads();
        lds[tid] += x;
        __syncthreads();
    }
    int excl = lds[tid] - c;
    sbase[tid] = p0 + excl;
    int node = (b << BSH) + tid;
    if (node < n) {
        rowptr[node] = p0 + excl;
        dinv[node] = rsqrtf(1.0f + (float)c);  // +1 self-loop
    }
    if (b == 0 && tid == 0) rowptr[n] = e;
    __syncthreads();
    for (int j = p0 + tid; j < p1; j += TPB) {
        int2 pr = pairs[j];
        int pos = atomicAdd(&sbase[pr.y & (TPB - 1)], 1);
        csr[pos] = pr.x;
    }
}

// xs[i][k] = x[i][k] * dinv[i]
template <int K>
__global__ __launch_bounds__(TPB) void prescale(const float* __restrict__ x,
                                                const float* __restrict__ dinv,
                                                float* __restrict__ xs, int n) {
    int idx = blockIdx.x * TPB + threadIdx.x;
    if (idx < n * K) xs[idx] = x[idx] * dinv[idx / K];
}

static __device__ __forceinline__ float4 f4add(float4 a, float4 b) {
    return make_float4(a.x + b.x, a.y + b.y, a.z + b.z, a.w + b.w);
}

// ---- aggregation: C/4 float4-lanes per node, unroll-8 gather ----
template <int C>
__global__ __launch_bounds__(TPB) void agg_kernel(const float* __restrict__ hs,
                                                  const int* __restrict__ rowptr,
                                                  const int* __restrict__ csr,
                                                  const float* __restrict__ dinv,
                                                  float* __restrict__ agg, int n) {
    constexpr int L = C / 4;         // float4 lanes per node
    const int NPB = TPB / L;
    int grp = threadIdx.x / L, cl = threadIdx.x % L;
    int i = blockIdx.x * NPB + grp;
    if (i >= n) return;
    const float4* hv = (const float4*)hs;
    float4 acc = hv[(size_t)i * L + cl];  // self-loop term
    float4 acc2 = make_float4(0.f, 0.f, 0.f, 0.f);
    int j = rowptr[i], re = rowptr[i + 1];
    for (; j + 8 <= re; j += 8) {
        int s0 = csr[j + 0], s1 = csr[j + 1], s2 = csr[j + 2], s3 = csr[j + 3];
        int s4 = csr[j + 4], s5 = csr[j + 5], s6 = csr[j + 6], s7 = csr[j + 7];
        float4 v0 = hv[(size_t)s0 * L + cl], v1 = hv[(size_t)s1 * L + cl];
        float4 v2 = hv[(size_t)s2 * L + cl], v3 = hv[(size_t)s3 * L + cl];
        float4 v4 = hv[(size_t)s4 * L + cl], v5 = hv[(size_t)s5 * L + cl];
        float4 v6 = hv[(size_t)s6 * L + cl], v7 = hv[(size_t)s7 * L + cl];
        acc  = f4add(acc,  f4add(f4add(v0, v1), f4add(v2, v3)));
        acc2 = f4add(acc2, f4add(f4add(v4, v5), f4add(v6, v7)));
    }
    if (j + 4 <= re) {
        int s0 = csr[j + 0], s1 = csr[j + 1], s2 = csr[j + 2], s3 = csr[j + 3];
        acc  = f4add(acc,  f4add(hv[(size_t)s0 * L + cl], hv[(size_t)s1 * L + cl]));
        acc2 = f4add(acc2, f4add(hv[(size_t)s2 * L + cl], hv[(size_t)s3 * L + cl]));
        j += 4;
    }
    for (; j < re; ++j) acc = f4add(acc, hv[(size_t)csr[j] * L + cl]);
    float di = dinv[i];
    float4 r = f4add(acc, acc2);
    r.x *= di; r.y *= di; r.z *= di; r.w *= di;
    ((float4*)agg)[(size_t)i * L + cl] = r;
}

// ---- dense transform: LDS-staged input tile, W K-chunks in registers ----
// Block owns NODES=64 consecutive nodes; the 64xK row-major tile is CONTIGUOUS
// in memory -> staging is a straight coalesced float4 copy. Compute reads rows
// from LDS (broadcast ds_read, all lanes of a slot hit the same address).
// out[i][c] = (relu?)( sum_k in[i][k]*W[k][c] + b[c] ) * (dinv[i] if SCALE)
template <int K, int C, bool RELU_OUT, bool SCALE_OUT>
__global__ __launch_bounds__(TPB) void xw_kernel(const float* __restrict__ in,
                                                 const float* __restrict__ W,
                                                 const float* __restrict__ b,
                                                 const float* __restrict__ dinv,
                                                 float* __restrict__ out, int n) {
    constexpr int NODES = 64;              // nodes per block
    constexpr int SLOTS = TPB / C;         // 4 (C=64) or 8 (C=32)
    constexpr int NPT = NODES / SLOTS;     // 16 or 8 nodes per thread
    constexpr int KT = (K > 16) ? 16 : K;  // W-column chunk in regs
    __shared__ float tile[NODES * K];      // K=64: 16 KB

    int i0 = blockIdx.x * NODES;
    // ---- stage (contiguous copy, coalesced) ----
    constexpr int TOTF4 = NODES * K / 4;
    const float4* gin = (const float4*)(in + (size_t)i0 * K);
    float4* st = (float4*)tile;
    int limF4 = (n - i0 >= NODES) ? TOTF4 : ((n - i0) * K) / 4;
#pragma unroll
    for (int t = threadIdx.x; t < TOTF4; t += TPB)
        st[t] = (t < limF4) ? gin[t] : make_float4(0.f, 0.f, 0.f, 0.f);
    __syncthreads();

    int c = threadIdx.x % C;
    int slot = threadIdx.x / C;
    float acc[NPT];
#pragma unroll
    for (int t = 0; t < NPT; ++t) acc[t] = 0.0f;

#pragma unroll
    for (int p = 0; p < K; p += KT) {
        float wc[KT];
#pragma unroll
        for (int k = 0; k < KT; ++k) wc[k] = W[(size_t)(p + k) * C + c];
#pragma unroll
        for (int t = 0; t < NPT; ++t) {
            const float4* row = (const float4*)(tile + (slot * NPT + t) * K + p);
#pragma unroll
            for (int q = 0; q < KT / 4; ++q) {
                float4 r = row[q];
                acc[t] = fmaf(r.x, wc[4 * q + 0], acc[t]);
                acc[t] = fmaf(r.y, wc[4 * q + 1], acc[t]);
                acc[t] = fmaf(r.z, wc[4 * q + 2], acc[t]);
                acc[t] = fmaf(r.w, wc[4 * q + 3], acc[t]);
            }
        }
    }
    float bc = b[c];
#pragma unroll
    for (int t = 0; t < NPT; ++t) {
        int i = i0 + slot * NPT + t;
        if (i < n) {
            float v = acc[t] + bc;
            if (RELU_OUT) v = fmaxf(v, 0.0f);
            if (SCALE_OUT) v *= dinv[i];
            out[(size_t)i * C + c] = v;  // coalesced
        }
    }
}

extern "C" void kernel_launch(void* const* d_in, const int* in_sizes, int n_in,
                              void* d_out, int out_size, void* d_ws, size_t ws_size,
                              hipStream_t stream) {
    const float* x  = (const float*)d_in[0];
    const int*   ei = (const int*)d_in[1];
    const float* W1 = (const float*)d_in[2];
    const float* b1 = (const float*)d_in[3];
    const float* W2 = (const float*)d_in[4];
    const float* b2 = (const float*)d_in[5];
    const float* W3 = (const float*)d_in[6];
    const float* b3 = (const float*)d_in[7];
    float* out = (float*)d_out;

    const int n = in_sizes[0] / 4;   // 100000
    const int e = in_sizes[1] / 2;   // 1600000
    const int* src = ei;
    const int* dst = ei + e;
    const int nb = cdiv(n, 1 << BSH);  // 391 buckets (NBMAX=512 slots)

    char* ws = (char*)d_ws;
    size_t off = 0;
    auto carve = [&](size_t bytes) {
        char* p = ws + off;
        off = (off + bytes + 255) & ~(size_t)255;
        return p;
    };
    float* dinv   = (float*)carve((size_t)n * 4);
    int*   rowptr = (int*)  carve((size_t)(n + 1) * 4);
    int*   bhist  = (int*)  carve((size_t)(NBMAX + 1) * 4);
    int*   boff   = (int*)  carve((size_t)(NBMAX + 1) * 4);
    int*   bcur   = (int*)  carve((size_t)(NBMAX + 1) * 4);
    int*   csr    = (int*)  carve((size_t)e * 4);
    float* A      = (float*)carve((size_t)n * 64 * 4);  // agg output; pairs aliases this
    float* B      = (float*)carve((size_t)n * 32 * 4);  // h1s
    float* xs     = (float*)carve((size_t)n * 4 * 4);   // prescaled x
    int2* pairs = (int2*)A;  // 12.8 MB <= 25.6 MB; consumed before A is first written

    const int eblk = cdiv(e, TPB * IPT);  // 196 blocks over edges

    // ---- CSR + norms (LDS-staged multisplit counting sort) ----
    bhist_zero<<<cdiv(NBMAX + 1, TPB), TPB, 0, stream>>>(bhist, NBMAX + 1);
    ms_hist<<<eblk, TPB, 0, stream>>>(dst, bhist, e);
    bscan<<<1, TPB, 0, stream>>>(bhist, boff, bcur);
    ms_scatter<<<eblk, TPB, 0, stream>>>(src, dst, bcur, pairs, e);
    build_csr<<<nb, TPB, 0, stream>>>(pairs, boff, rowptr, dinv, csr, n, e);

    // ---- layer 1: xs = x*dinv; agg C=4; h1s = relu(agg@W1+b1)*dinv [n,32] ----
    prescale<4><<<cdiv((long long)n * 4, TPB), TPB, 0, stream>>>(x, dinv, xs, n);
    agg_kernel<4><<<cdiv(n, TPB), TPB, 0, stream>>>(xs, rowptr, csr, dinv, A, n);
    xw_kernel<4, 32, true, true><<<cdiv(n, 64), TPB, 0, stream>>>(A, W1, b1, dinv, B, n);

    // ---- layer 2: agg C=32; h2s = relu(agg@W2+b2)*dinv [n,64] (in d_out) ----
    agg_kernel<32><<<cdiv(n, TPB / 8), TPB, 0, stream>>>(B, rowptr, csr, dinv, A, n);
    xw_kernel<32, 64, true, true><<<cdiv(n, 64), TPB, 0, stream>>>(A, W2, b2, dinv, out, n);

    // ---- layer 3: agg C=64; out = agg@W3+b3 ----
    agg_kernel<64><<<cdiv(n, TPB / 16), TPB, 0, stream>>>(out, rowptr, csr, dinv, A, n);
    xw_kernel<64, 64, false, false><<<cdiv(n, 64), TPB, 0, stream>>>(A, W3, b3, dinv, out, n);
}

// Round 9
// 219.014 us; speedup vs baseline: 3.1498x; 3.1498x over previous
//
#include <hip/hip_runtime.h>

// 3-layer GCN, pull-mode CSR gather, aggregate-before-transform, prescaled features.
// CSR build = 2-pass LDS-staged multisplit counting sort (bucket = dst>>8).
// xw transform (R9): LDS-staged tile of 32 contiguous nodes (contiguous copy),
// W K-chunks (KT=16) in regs, acc[NPT<=8] in regs, p-loop NOT unrolled.
// R8 lesson: full p x t x q unroll (NPT=16) -> 256-VGPR spill, 1.4 GB scratch
// traffic per dispatch. Bound the live set; let only the inner chunk unroll.
// agg: float4 lanes (C/4 lanes per node) -> 4x rows in flight per gather instr.

#define TPB 256
#define BSH 8                 // 256 nodes per bucket
#define NBMAX 512             // LDS histogram slots (nb = 391 actual)
#define IPT 32                // edges per thread -> 8192 edges per block

static inline int cdiv(long long a, int b) { return (int)((a + b - 1) / b); }

__global__ __launch_bounds__(TPB) void bhist_zero(int* __restrict__ bhist, int m) {
    int i = blockIdx.x * TPB + threadIdx.x;
    if (i < m) bhist[i] = 0;
}

__global__ __launch_bounds__(TPB) void ms_hist(const int* __restrict__ dst,
                                               int* __restrict__ bhist, int e) {
    __shared__ int h[NBMAX];
    int tid = threadIdx.x;
    h[tid] = 0; h[tid + TPB] = 0;
    __syncthreads();
    int base = blockIdx.x * (TPB * IPT);
#pragma unroll 8
    for (int k = 0; k < IPT; ++k) {
        int i = base + k * TPB + tid;
        if (i < e) atomicAdd(&h[dst[i] >> BSH], 1);
    }
    __syncthreads();
    int v0 = h[tid], v1 = h[tid + TPB];
    if (v0) atomicAdd(&bhist[tid], v0);
    if (v1) atomicAdd(&bhist[tid + TPB], v1);
}

// single-block exclusive scan of bhist[NBMAX] -> boff/bcur[0..NBMAX]
__global__ __launch_bounds__(TPB) void bscan(const int* __restrict__ bhist,
                                             int* __restrict__ boff,
                                             int* __restrict__ bcur) {
    __shared__ int lds[TPB];
    int tid = threadIdx.x;
    int a = bhist[2 * tid], b = bhist[2 * tid + 1];
    int s = a + b;
    lds[tid] = s;
    __syncthreads();
    for (int off = 1; off < TPB; off <<= 1) {
        int x = (tid >= off) ? lds[tid - off] : 0;
        __syncthreads();
        lds[tid] += x;
        __syncthreads();
    }
    int excl = lds[tid] - s;
    boff[2 * tid] = excl;       bcur[2 * tid] = excl;
    boff[2 * tid + 1] = excl + a; bcur[2 * tid + 1] = excl + a;
    if (tid == TPB - 1) { boff[NBMAX] = lds[TPB - 1]; bcur[NBMAX] = lds[TPB - 1]; }
}

__global__ __launch_bounds__(TPB) void ms_scatter(const int* __restrict__ src,
                                                  const int* __restrict__ dst,
                                                  int* __restrict__ bcur,
                                                  int2* __restrict__ pairs, int e) {
    __shared__ int h[NBMAX];
    __shared__ int sbase[NBMAX];
    int tid = threadIdx.x;
    h[tid] = 0; h[tid + TPB] = 0;
    __syncthreads();
    int base = blockIdx.x * (TPB * IPT);
#pragma unroll 8
    for (int k = 0; k < IPT; ++k) {
        int i = base + k * TPB + tid;
        if (i < e) atomicAdd(&h[dst[i] >> BSH], 1);
    }
    __syncthreads();
    int v0 = h[tid], v1 = h[tid + TPB];
    if (v0) sbase[tid] = atomicAdd(&bcur[tid], v0);
    if (v1) sbase[tid + TPB] = atomicAdd(&bcur[tid + TPB], v1);
    __syncthreads();
#pragma unroll 8
    for (int k = 0; k < IPT; ++k) {
        int i = base + k * TPB + tid;
        if (i < e) {
            int s = src[i], d = dst[i];
            int pos = atomicAdd(&sbase[d >> BSH], 1);
            pairs[pos] = make_int2(s, d);
        }
    }
}

// one WG per bucket: histogram -> scan -> rowptr/dinv -> csr placement
__global__ __launch_bounds__(TPB) void build_csr(const int2* __restrict__ pairs,
                                                 const int* __restrict__ boff,
                                                 int* __restrict__ rowptr,
                                                 float* __restrict__ dinv,
                                                 int* __restrict__ csr, int n, int e) {
    int b = blockIdx.x;
    int p0 = boff[b], p1 = boff[b + 1];
    __shared__ int scnt[TPB];
    __shared__ int sbase[TPB];
    __shared__ int lds[TPB];
    int tid = threadIdx.x;
    scnt[tid] = 0;
    __syncthreads();
    for (int j = p0 + tid; j < p1; j += TPB)
        atomicAdd(&scnt[pairs[j].y & (TPB - 1)], 1);
    __syncthreads();
    int c = scnt[tid];
    lds[tid] = c;
    __syncthreads();
    for (int off = 1; off < TPB; off <<= 1) {
        int x = (tid >= off) ? lds[tid - off] : 0;
        __syncthreads();
        lds[tid] += x;
        __syncthreads();
    }
    int excl = lds[tid] - c;
    sbase[tid] = p0 + excl;
    int node = (b << BSH) + tid;
    if (node < n) {
        rowptr[node] = p0 + excl;
        dinv[node] = rsqrtf(1.0f + (float)c);  // +1 self-loop
    }
    if (b == 0 && tid == 0) rowptr[n] = e;
    __syncthreads();
    for (int j = p0 + tid; j < p1; j += TPB) {
        int2 pr = pairs[j];
        int pos = atomicAdd(&sbase[pr.y & (TPB - 1)], 1);
        csr[pos] = pr.x;
    }
}

// xs[i][k] = x[i][k] * dinv[i]
template <int K>
__global__ __launch_bounds__(TPB) void prescale(const float* __restrict__ x,
                                                const float* __restrict__ dinv,
                                                float* __restrict__ xs, int n) {
    int idx = blockIdx.x * TPB + threadIdx.x;
    if (idx < n * K) xs[idx] = x[idx] * dinv[idx / K];
}

static __device__ __forceinline__ float4 f4add(float4 a, float4 b) {
    return make_float4(a.x + b.x, a.y + b.y, a.z + b.z, a.w + b.w);
}

// ---- aggregation: C/4 float4-lanes per node, unroll-8 gather ----
template <int C>
__global__ __launch_bounds__(TPB) void agg_kernel(const float* __restrict__ hs,
                                                  const int* __restrict__ rowptr,
                                                  const int* __restrict__ csr,
                                                  const float* __restrict__ dinv,
                                                  float* __restrict__ agg, int n) {
    constexpr int L = C / 4;         // float4 lanes per node
    const int NPB = TPB / L;
    int grp = threadIdx.x / L, cl = threadIdx.x % L;
    int i = blockIdx.x * NPB + grp;
    if (i >= n) return;
    const float4* hv = (const float4*)hs;
    float4 acc = hv[(size_t)i * L + cl];  // self-loop term
    float4 acc2 = make_float4(0.f, 0.f, 0.f, 0.f);
    int j = rowptr[i], re = rowptr[i + 1];
    for (; j + 8 <= re; j += 8) {
        int s0 = csr[j + 0], s1 = csr[j + 1], s2 = csr[j + 2], s3 = csr[j + 3];
        int s4 = csr[j + 4], s5 = csr[j + 5], s6 = csr[j + 6], s7 = csr[j + 7];
        float4 v0 = hv[(size_t)s0 * L + cl], v1 = hv[(size_t)s1 * L + cl];
        float4 v2 = hv[(size_t)s2 * L + cl], v3 = hv[(size_t)s3 * L + cl];
        float4 v4 = hv[(size_t)s4 * L + cl], v5 = hv[(size_t)s5 * L + cl];
        float4 v6 = hv[(size_t)s6 * L + cl], v7 = hv[(size_t)s7 * L + cl];
        acc  = f4add(acc,  f4add(f4add(v0, v1), f4add(v2, v3)));
        acc2 = f4add(acc2, f4add(f4add(v4, v5), f4add(v6, v7)));
    }
    if (j + 4 <= re) {
        int s0 = csr[j + 0], s1 = csr[j + 1], s2 = csr[j + 2], s3 = csr[j + 3];
        acc  = f4add(acc,  f4add(hv[(size_t)s0 * L + cl], hv[(size_t)s1 * L + cl]));
        acc2 = f4add(acc2, f4add(hv[(size_t)s2 * L + cl], hv[(size_t)s3 * L + cl]));
        j += 4;
    }
    for (; j < re; ++j) acc = f4add(acc, hv[(size_t)csr[j] * L + cl]);
    float di = dinv[i];
    float4 r = f4add(acc, acc2);
    r.x *= di; r.y *= di; r.z *= di; r.w *= di;
    ((float4*)agg)[(size_t)i * L + cl] = r;
}

// ---- dense transform: LDS-staged 32-node tile, W K-chunks in regs ----
// Block owns NODES=32 consecutive nodes (100000 = 3125*32 -> no tail).
// Staging is a contiguous coalesced float4 copy. Compute reads rows from LDS
// (broadcast ds_read). p-loop deliberately NOT unrolled: only one wc[KT] chunk
// and acc[NPT] live at a time (~45 VGPR, no spill).
// out[i][c] = (relu?)( sum_k in[i][k]*W[k][c] + b[c] ) * (dinv[i] if SCALE)
template <int K, int C, bool RELU_OUT, bool SCALE_OUT>
__global__ __launch_bounds__(TPB) void xw_kernel(const float* __restrict__ in,
                                                 const float* __restrict__ W,
                                                 const float* __restrict__ b,
                                                 const float* __restrict__ dinv,
                                                 float* __restrict__ out, int n) {
    constexpr int NODES = 32;              // nodes per block
    constexpr int SLOTS = TPB / C;         // 4 (C=64) or 8 (C=32)
    constexpr int NPT = NODES / SLOTS;     // 8 or 4 nodes per thread
    constexpr int KT = (K > 16) ? 16 : K;  // W-column chunk in regs
    __shared__ float tile[NODES * K];      // K=64: 8 KB

    int i0 = blockIdx.x * NODES;
    // ---- stage (contiguous copy, coalesced) ----
    constexpr int TOTF4 = NODES * K / 4;
    const float4* gin = (const float4*)(in + (size_t)i0 * K);
    float4* st = (float4*)tile;
    int limF4 = (n - i0 >= NODES) ? TOTF4 : ((n - i0) * K) / 4;
    for (int t = threadIdx.x; t < TOTF4; t += TPB)
        st[t] = (t < limF4) ? gin[t] : make_float4(0.f, 0.f, 0.f, 0.f);
    __syncthreads();

    int c = threadIdx.x % C;
    int slot = threadIdx.x / C;
    float acc[NPT];
#pragma unroll
    for (int t = 0; t < NPT; ++t) acc[t] = 0.0f;

#pragma unroll 1
    for (int p = 0; p < K; p += KT) {
        float wc[KT];
#pragma unroll
        for (int k = 0; k < KT; ++k) wc[k] = W[(size_t)(p + k) * C + c];
#pragma unroll
        for (int t = 0; t < NPT; ++t) {
            const float4* row = (const float4*)(tile + (slot * NPT + t) * K + p);
#pragma unroll
            for (int q = 0; q < KT / 4; ++q) {
                float4 r = row[q];
                acc[t] = fmaf(r.x, wc[4 * q + 0], acc[t]);
                acc[t] = fmaf(r.y, wc[4 * q + 1], acc[t]);
                acc[t] = fmaf(r.z, wc[4 * q + 2], acc[t]);
                acc[t] = fmaf(r.w, wc[4 * q + 3], acc[t]);
            }
        }
    }
    float bc = b[c];
#pragma unroll
    for (int t = 0; t < NPT; ++t) {
        int i = i0 + slot * NPT + t;
        if (i < n) {
            float v = acc[t] + bc;
            if (RELU_OUT) v = fmaxf(v, 0.0f);
            if (SCALE_OUT) v *= dinv[i];
            out[(size_t)i * C + c] = v;  // coalesced
        }
    }
}

extern "C" void kernel_launch(void* const* d_in, const int* in_sizes, int n_in,
                              void* d_out, int out_size, void* d_ws, size_t ws_size,
                              hipStream_t stream) {
    const float* x  = (const float*)d_in[0];
    const int*   ei = (const int*)d_in[1];
    const float* W1 = (const float*)d_in[2];
    const float* b1 = (const float*)d_in[3];
    const float* W2 = (const float*)d_in[4];
    const float* b2 = (const float*)d_in[5];
    const float* W3 = (const float*)d_in[6];
    const float* b3 = (const float*)d_in[7];
    float* out = (float*)d_out;

    const int n = in_sizes[0] / 4;   // 100000
    const int e = in_sizes[1] / 2;   // 1600000
    const int* src = ei;
    const int* dst = ei + e;
    const int nb = cdiv(n, 1 << BSH);  // 391 buckets (NBMAX=512 slots)

    char* ws = (char*)d_ws;
    size_t off = 0;
    auto carve = [&](size_t bytes) {
        char* p = ws + off;
        off = (off + bytes + 255) & ~(size_t)255;
        return p;
    };
    float* dinv   = (float*)carve((size_t)n * 4);
    int*   rowptr = (int*)  carve((size_t)(n + 1) * 4);
    int*   bhist  = (int*)  carve((size_t)(NBMAX + 1) * 4);
    int*   boff   = (int*)  carve((size_t)(NBMAX + 1) * 4);
    int*   bcur   = (int*)  carve((size_t)(NBMAX + 1) * 4);
    int*   csr    = (int*)  carve((size_t)e * 4);
    float* A      = (float*)carve((size_t)n * 64 * 4);  // agg output; pairs aliases this
    float* B      = (float*)carve((size_t)n * 32 * 4);  // h1s
    float* xs     = (float*)carve((size_t)n * 4 * 4);   // prescaled x
    int2* pairs = (int2*)A;  // 12.8 MB <= 25.6 MB; consumed before A is first written

    const int eblk = cdiv(e, TPB * IPT);  // 196 blocks over edges

    // ---- CSR + norms (LDS-staged multisplit counting sort) ----
    bhist_zero<<<cdiv(NBMAX + 1, TPB), TPB, 0, stream>>>(bhist, NBMAX + 1);
    ms_hist<<<eblk, TPB, 0, stream>>>(dst, bhist, e);
    bscan<<<1, TPB, 0, stream>>>(bhist, boff, bcur);
    ms_scatter<<<eblk, TPB, 0, stream>>>(src, dst, bcur, pairs, e);
    build_csr<<<nb, TPB, 0, stream>>>(pairs, boff, rowptr, dinv, csr, n, e);

    // ---- layer 1: xs = x*dinv; agg C=4; h1s = relu(agg@W1+b1)*dinv [n,32] ----
    prescale<4><<<cdiv((long long)n * 4, TPB), TPB, 0, stream>>>(x, dinv, xs, n);
    agg_kernel<4><<<cdiv(n, TPB), TPB, 0, stream>>>(xs, rowptr, csr, dinv, A, n);
    xw_kernel<4, 32, true, true><<<cdiv(n, 32), TPB, 0, stream>>>(A, W1, b1, dinv, B, n);

    // ---- layer 2: agg C=32; h2s = relu(agg@W2+b2)*dinv [n,64] (in d_out) ----
    agg_kernel<32><<<cdiv(n, TPB / 8), TPB, 0, stream>>>(B, rowptr, csr, dinv, A, n);
    xw_kernel<32, 64, true, true><<<cdiv(n, 32), TPB, 0, stream>>>(A, W2, b2, dinv, out, n);

    // ---- layer 3: agg C=64; out = agg@W3+b3 ----
    agg_kernel<64><<<cdiv(n, TPB / 16), TPB, 0, stream>>>(out, rowptr, csr, dinv, A, n);
    xw_kernel<64, 64, false, false><<<cdiv(n, 32), TPB, 0, stream>>>(A, W3, b3, dinv, out, n);
}

// Round 10
// 207.434 us; speedup vs baseline: 3.3256x; 1.0558x over previous
//
#include <hip/hip_runtime.h>

// 3-layer GCN, pull-mode CSR gather, aggregate-before-transform, prescaled features.
// CSR build = 2-pass LDS-staged multisplit counting sort (bucket = dst>>8).
// R10: agg+xw FUSED per layer — agg writes the NODES x K tile to LDS, xw phase
// reads it back (broadcast ds_read) with W K-chunks in regs. Removes the A
// intermediate round-trip (~77 MB) and halves launch count. R8/R9 lessons kept:
// p-loop and round-loop NOT unrolled (bounded live set, no spill).

#define TPB 256
#define BSH 8                 // 256 nodes per bucket
#define NBMAX 512             // LDS histogram slots (nb = 391 actual)
#define IPT 32                // edges per thread -> 8192 edges per block

static inline int cdiv(long long a, int b) { return (int)((a + b - 1) / b); }

__global__ __launch_bounds__(TPB) void bhist_zero(int* __restrict__ bhist, int m) {
    int i = blockIdx.x * TPB + threadIdx.x;
    if (i < m) bhist[i] = 0;
}

__global__ __launch_bounds__(TPB) void ms_hist(const int* __restrict__ dst,
                                               int* __restrict__ bhist, int e) {
    __shared__ int h[NBMAX];
    int tid = threadIdx.x;
    h[tid] = 0; h[tid + TPB] = 0;
    __syncthreads();
    int base = blockIdx.x * (TPB * IPT);
#pragma unroll 8
    for (int k = 0; k < IPT; ++k) {
        int i = base + k * TPB + tid;
        if (i < e) atomicAdd(&h[dst[i] >> BSH], 1);
    }
    __syncthreads();
    int v0 = h[tid], v1 = h[tid + TPB];
    if (v0) atomicAdd(&bhist[tid], v0);
    if (v1) atomicAdd(&bhist[tid + TPB], v1);
}

// single-block exclusive scan of bhist[NBMAX] -> boff/bcur[0..NBMAX]
__global__ __launch_bounds__(TPB) void bscan(const int* __restrict__ bhist,
                                             int* __restrict__ boff,
                                             int* __restrict__ bcur) {
    __shared__ int lds[TPB];
    int tid = threadIdx.x;
    int a = bhist[2 * tid], b = bhist[2 * tid + 1];
    int s = a + b;
    lds[tid] = s;
    __syncthreads();
    for (int off = 1; off < TPB; off <<= 1) {
        int x = (tid >= off) ? lds[tid - off] : 0;
        __syncthreads();
        lds[tid] += x;
        __syncthreads();
    }
    int excl = lds[tid] - s;
    boff[2 * tid] = excl;       bcur[2 * tid] = excl;
    boff[2 * tid + 1] = excl + a; bcur[2 * tid + 1] = excl + a;
    if (tid == TPB - 1) { boff[NBMAX] = lds[TPB - 1]; bcur[NBMAX] = lds[TPB - 1]; }
}

__global__ __launch_bounds__(TPB) void ms_scatter(const int* __restrict__ src,
                                                  const int* __restrict__ dst,
                                                  int* __restrict__ bcur,
                                                  int2* __restrict__ pairs, int e) {
    __shared__ int h[NBMAX];
    __shared__ int sbase[NBMAX];
    int tid = threadIdx.x;
    h[tid] = 0; h[tid + TPB] = 0;
    __syncthreads();
    int base = blockIdx.x * (TPB * IPT);
#pragma unroll 8
    for (int k = 0; k < IPT; ++k) {
        int i = base + k * TPB + tid;
        if (i < e) atomicAdd(&h[dst[i] >> BSH], 1);
    }
    __syncthreads();
    int v0 = h[tid], v1 = h[tid + TPB];
    if (v0) sbase[tid] = atomicAdd(&bcur[tid], v0);
    if (v1) sbase[tid + TPB] = atomicAdd(&bcur[tid + TPB], v1);
    __syncthreads();
#pragma unroll 8
    for (int k = 0; k < IPT; ++k) {
        int i = base + k * TPB + tid;
        if (i < e) {
            int s = src[i], d = dst[i];
            int pos = atomicAdd(&sbase[d >> BSH], 1);
            pairs[pos] = make_int2(s, d);
        }
    }
}

// one WG per bucket: histogram -> scan -> rowptr/dinv -> csr placement
__global__ __launch_bounds__(TPB) void build_csr(const int2* __restrict__ pairs,
                                                 const int* __restrict__ boff,
                                                 int* __restrict__ rowptr,
                                                 float* __restrict__ dinv,
                                                 int* __restrict__ csr, int n, int e) {
    int b = blockIdx.x;
    int p0 = boff[b], p1 = boff[b + 1];
    __shared__ int scnt[TPB];
    __shared__ int sbase[TPB];
    __shared__ int lds[TPB];
    int tid = threadIdx.x;
    scnt[tid] = 0;
    __syncthreads();
    for (int j = p0 + tid; j < p1; j += TPB)
        atomicAdd(&scnt[pairs[j].y & (TPB - 1)], 1);
    __syncthreads();
    int c = scnt[tid];
    lds[tid] = c;
    __syncthreads();
    for (int off = 1; off < TPB; off <<= 1) {
        int x = (tid >= off) ? lds[tid - off] : 0;
        __syncthreads();
        lds[tid] += x;
        __syncthreads();
    }
    int excl = lds[tid] - c;
    sbase[tid] = p0 + excl;
    int node = (b << BSH) + tid;
    if (node < n) {
        rowptr[node] = p0 + excl;
        dinv[node] = rsqrtf(1.0f + (float)c);  // +1 self-loop
    }
    if (b == 0 && tid == 0) rowptr[n] = e;
    __syncthreads();
    for (int j = p0 + tid; j < p1; j += TPB) {
        int2 pr = pairs[j];
        int pos = atomicAdd(&sbase[pr.y & (TPB - 1)], 1);
        csr[pos] = pr.x;
    }
}

// xs[i][k] = x[i][k] * dinv[i]
template <int K>
__global__ __launch_bounds__(TPB) void prescale(const float* __restrict__ x,
                                                const float* __restrict__ dinv,
                                                float* __restrict__ xs, int n) {
    int idx = blockIdx.x * TPB + threadIdx.x;
    if (idx < n * K) xs[idx] = x[idx] * dinv[idx / K];
}

static __device__ __forceinline__ float4 f4add(float4 a, float4 b) {
    return make_float4(a.x + b.x, a.y + b.y, a.z + b.z, a.w + b.w);
}

// ---- fused layer: agg (gather into LDS tile) + dense transform ----
// Phase A: K/4 float4-lanes per node, unroll-8 gather, result -> LDS tile.
// Phase B: out[i][c] = (relu?)( sum_k tile[i][k]*W[k][c] + b[c] ) * (dinv[i]?)
template <int K, int CO, int NODES, bool RELU_OUT, bool SCALE_OUT>
__global__ __launch_bounds__(TPB) void fused_layer(const float* __restrict__ hs,
                                                   const int* __restrict__ rowptr,
                                                   const int* __restrict__ csr,
                                                   const float* __restrict__ dinv,
                                                   const float* __restrict__ W,
                                                   const float* __restrict__ bias,
                                                   float* __restrict__ out, int n) {
    constexpr int L = K / 4;           // float4 lanes per node (agg phase)
    constexpr int NGRP = TPB / L;      // node-groups per round
    constexpr int ROUNDS = NODES / NGRP;
    __shared__ float tile[NODES * K];  // max 8 KB (32x64)
    float4* tf4 = (float4*)tile;

    int i0 = blockIdx.x * NODES;
    int cl = threadIdx.x % L;
    int grp = threadIdx.x / L;

#pragma unroll 1
    for (int r = 0; r < ROUNDS; ++r) {
        int ln = r * NGRP + grp;
        int i = i0 + ln;
        if (i < n) {
            const float4* hv = (const float4*)hs;
            float4 acc = hv[(size_t)i * L + cl];  // self-loop term
            float4 acc2 = make_float4(0.f, 0.f, 0.f, 0.f);
            int j = rowptr[i], re = rowptr[i + 1];
            for (; j + 8 <= re; j += 8) {
                int s0 = csr[j + 0], s1 = csr[j + 1], s2 = csr[j + 2], s3 = csr[j + 3];
                int s4 = csr[j + 4], s5 = csr[j + 5], s6 = csr[j + 6], s7 = csr[j + 7];
                float4 v0 = hv[(size_t)s0 * L + cl], v1 = hv[(size_t)s1 * L + cl];
                float4 v2 = hv[(size_t)s2 * L + cl], v3 = hv[(size_t)s3 * L + cl];
                float4 v4 = hv[(size_t)s4 * L + cl], v5 = hv[(size_t)s5 * L + cl];
                float4 v6 = hv[(size_t)s6 * L + cl], v7 = hv[(size_t)s7 * L + cl];
                acc  = f4add(acc,  f4add(f4add(v0, v1), f4add(v2, v3)));
                acc2 = f4add(acc2, f4add(f4add(v4, v5), f4add(v6, v7)));
            }
            if (j + 4 <= re) {
                int s0 = csr[j + 0], s1 = csr[j + 1], s2 = csr[j + 2], s3 = csr[j + 3];
                acc  = f4add(acc,  f4add(hv[(size_t)s0 * L + cl], hv[(size_t)s1 * L + cl]));
                acc2 = f4add(acc2, f4add(hv[(size_t)s2 * L + cl], hv[(size_t)s3 * L + cl]));
                j += 4;
            }
            for (; j < re; ++j) acc = f4add(acc, hv[(size_t)csr[j] * L + cl]);
            float di = dinv[i];
            float4 rr = f4add(acc, acc2);
            rr.x *= di; rr.y *= di; rr.z *= di; rr.w *= di;
            tf4[ln * L + cl] = rr;
        }
    }
    __syncthreads();

    // ---- phase B: dense transform from LDS tile ----
    constexpr int SLOTS = TPB / CO;
    constexpr int NPT = NODES / SLOTS;
    constexpr int KT = (K > 16) ? 16 : K;
    int c = threadIdx.x % CO;
    int slot = threadIdx.x / CO;

    float acc[NPT];
#pragma unroll
    for (int t = 0; t < NPT; ++t) acc[t] = 0.0f;

#pragma unroll 1
    for (int p = 0; p < K; p += KT) {
        float wc[KT];
#pragma unroll
        for (int k = 0; k < KT; ++k) wc[k] = W[(size_t)(p + k) * CO + c];
#pragma unroll
        for (int t = 0; t < NPT; ++t) {
            const float4* row = (const float4*)(tile + (slot * NPT + t) * K + p);
#pragma unroll
            for (int q = 0; q < KT / 4; ++q) {
                float4 r = row[q];
                acc[t] = fmaf(r.x, wc[4 * q + 0], acc[t]);
                acc[t] = fmaf(r.y, wc[4 * q + 1], acc[t]);
                acc[t] = fmaf(r.z, wc[4 * q + 2], acc[t]);
                acc[t] = fmaf(r.w, wc[4 * q + 3], acc[t]);
            }
        }
    }
    float bc = bias[c];
#pragma unroll
    for (int t = 0; t < NPT; ++t) {
        int i = i0 + slot * NPT + t;
        if (i < n) {
            float v = acc[t] + bc;
            if (RELU_OUT) v = fmaxf(v, 0.0f);
            if (SCALE_OUT) v *= dinv[i];
            out[(size_t)i * CO + c] = v;  // coalesced
        }
    }
}

extern "C" void kernel_launch(void* const* d_in, const int* in_sizes, int n_in,
                              void* d_out, int out_size, void* d_ws, size_t ws_size,
                              hipStream_t stream) {
    const float* x  = (const float*)d_in[0];
    const int*   ei = (const int*)d_in[1];
    const float* W1 = (const float*)d_in[2];
    const float* b1 = (const float*)d_in[3];
    const float* W2 = (const float*)d_in[4];
    const float* b2 = (const float*)d_in[5];
    const float* W3 = (const float*)d_in[6];
    const float* b3 = (const float*)d_in[7];
    float* out = (float*)d_out;

    const int n = in_sizes[0] / 4;   // 100000
    const int e = in_sizes[1] / 2;   // 1600000
    const int* src = ei;
    const int* dst = ei + e;
    const int nb = cdiv(n, 1 << BSH);  // 391 buckets (NBMAX=512 slots)

    char* ws = (char*)d_ws;
    size_t off = 0;
    auto carve = [&](size_t bytes) {
        char* p = ws + off;
        off = (off + bytes + 255) & ~(size_t)255;
        return p;
    };
    float* dinv   = (float*)carve((size_t)n * 4);
    int*   rowptr = (int*)  carve((size_t)(n + 1) * 4);
    int*   bhist  = (int*)  carve((size_t)(NBMAX + 1) * 4);
    int*   boff   = (int*)  carve((size_t)(NBMAX + 1) * 4);
    int*   bcur   = (int*)  carve((size_t)(NBMAX + 1) * 4);
    int*   csr    = (int*)  carve((size_t)e * 4);
    float* A      = (float*)carve((size_t)n * 64 * 4);  // h2s; pairs aliases this
    float* B      = (float*)carve((size_t)n * 32 * 4);  // h1s
    float* xs     = (float*)carve((size_t)n * 4 * 4);   // prescaled x
    int2* pairs = (int2*)A;  // 12.8 MB <= 25.6 MB; consumed before A is first written

    const int eblk = cdiv(e, TPB * IPT);  // 196 blocks over edges

    // ---- CSR + norms (LDS-staged multisplit counting sort) ----
    bhist_zero<<<cdiv(NBMAX + 1, TPB), TPB, 0, stream>>>(bhist, NBMAX + 1);
    ms_hist<<<eblk, TPB, 0, stream>>>(dst, bhist, e);
    bscan<<<1, TPB, 0, stream>>>(bhist, boff, bcur);
    ms_scatter<<<eblk, TPB, 0, stream>>>(src, dst, bcur, pairs, e);
    build_csr<<<nb, TPB, 0, stream>>>(pairs, boff, rowptr, dinv, csr, n, e);

    // ---- layer 1: xs = x*dinv; fused agg(C=4)+xw(4->32) -> B (h1s) ----
    prescale<4><<<cdiv((long long)n * 4, TPB), TPB, 0, stream>>>(x, dinv, xs, n);
    fused_layer<4, 32, 256, true, true><<<cdiv(n, 256), TPB, 0, stream>>>(
        xs, rowptr, csr, dinv, W1, b1, B, n);

    // ---- layer 2: fused agg(C=32)+xw(32->64) -> A (h2s) ----
    fused_layer<32, 64, 32, true, true><<<cdiv(n, 32), TPB, 0, stream>>>(
        B, rowptr, csr, dinv, W2, b2, A, n);

    // ---- layer 3: fused agg(C=64)+xw(64->64) -> out ----
    fused_layer<64, 64, 32, false, false><<<cdiv(n, 32), TPB, 0, stream>>>(
        A, rowptr, csr, dinv, W3, b3, out, n);
}

// Round 11
// 177.788 us; speedup vs baseline: 3.8802x; 1.1668x over previous
//
#include <hip/hip_runtime.h>
#include <hip/hip_fp16.h>

// 3-layer GCN, pull-mode CSR gather, aggregate-before-transform, prescaled features.
// CSR build = 2-pass LDS-staged multisplit counting sort (bucket = dst>>8).
// R11: gathered feature arrays stored FP16 (xs, h1s, h2s) — halves the random-
// gather traffic that bounds layers 2/3 (R9/R10: 187 MB L2-fill @ ~3 TB/s).
// All arithmetic f32; conversion in registers. R8/R9 lessons kept: phase-B
// works on 32-node sub-blocks (acc[8]+wc[16]), p-loop/round-loops unroll 1,
// all acc[] indices compile-time (full unroll) to avoid scratch.

#define TPB 256
#define BSH 8                 // 256 nodes per bucket
#define NBMAX 512             // LDS histogram slots (nb = 391 actual)
#define IPT 32                // edges per thread -> 8192 edges per block

static inline int cdiv(long long a, int b) { return (int)((a + b - 1) / b); }

struct alignas(16) h8 { __half2 a, b, c, d; };  // 8 halves = 16 B
struct alignas(8)  h4 { __half2 a, b; };        // 4 halves = 8 B

__global__ __launch_bounds__(TPB) void bhist_zero(int* __restrict__ bhist, int m) {
    int i = blockIdx.x * TPB + threadIdx.x;
    if (i < m) bhist[i] = 0;
}

__global__ __launch_bounds__(TPB) void ms_hist(const int* __restrict__ dst,
                                               int* __restrict__ bhist, int e) {
    __shared__ int h[NBMAX];
    int tid = threadIdx.x;
    h[tid] = 0; h[tid + TPB] = 0;
    __syncthreads();
    int base = blockIdx.x * (TPB * IPT);
#pragma unroll 8
    for (int k = 0; k < IPT; ++k) {
        int i = base + k * TPB + tid;
        if (i < e) atomicAdd(&h[dst[i] >> BSH], 1);
    }
    __syncthreads();
    int v0 = h[tid], v1 = h[tid + TPB];
    if (v0) atomicAdd(&bhist[tid], v0);
    if (v1) atomicAdd(&bhist[tid + TPB], v1);
}

// single-block exclusive scan of bhist[NBMAX] -> boff/bcur[0..NBMAX]
__global__ __launch_bounds__(TPB) void bscan(const int* __restrict__ bhist,
                                             int* __restrict__ boff,
                                             int* __restrict__ bcur) {
    __shared__ int lds[TPB];
    int tid = threadIdx.x;
    int a = bhist[2 * tid], b = bhist[2 * tid + 1];
    int s = a + b;
    lds[tid] = s;
    __syncthreads();
    for (int off = 1; off < TPB; off <<= 1) {
        int x = (tid >= off) ? lds[tid - off] : 0;
        __syncthreads();
        lds[tid] += x;
        __syncthreads();
    }
    int excl = lds[tid] - s;
    boff[2 * tid] = excl;       bcur[2 * tid] = excl;
    boff[2 * tid + 1] = excl + a; bcur[2 * tid + 1] = excl + a;
    if (tid == TPB - 1) { boff[NBMAX] = lds[TPB - 1]; bcur[NBMAX] = lds[TPB - 1]; }
}

__global__ __launch_bounds__(TPB) void ms_scatter(const int* __restrict__ src,
                                                  const int* __restrict__ dst,
                                                  int* __restrict__ bcur,
                                                  int2* __restrict__ pairs, int e) {
    __shared__ int h[NBMAX];
    __shared__ int sbase[NBMAX];
    int tid = threadIdx.x;
    h[tid] = 0; h[tid + TPB] = 0;
    __syncthreads();
    int base = blockIdx.x * (TPB * IPT);
#pragma unroll 8
    for (int k = 0; k < IPT; ++k) {
        int i = base + k * TPB + tid;
        if (i < e) atomicAdd(&h[dst[i] >> BSH], 1);
    }
    __syncthreads();
    int v0 = h[tid], v1 = h[tid + TPB];
    if (v0) sbase[tid] = atomicAdd(&bcur[tid], v0);
    if (v1) sbase[tid + TPB] = atomicAdd(&bcur[tid + TPB], v1);
    __syncthreads();
#pragma unroll 8
    for (int k = 0; k < IPT; ++k) {
        int i = base + k * TPB + tid;
        if (i < e) {
            int s = src[i], d = dst[i];
            int pos = atomicAdd(&sbase[d >> BSH], 1);
            pairs[pos] = make_int2(s, d);
        }
    }
}

// one WG per bucket: histogram -> scan -> rowptr/dinv -> csr placement
__global__ __launch_bounds__(TPB) void build_csr(const int2* __restrict__ pairs,
                                                 const int* __restrict__ boff,
                                                 int* __restrict__ rowptr,
                                                 float* __restrict__ dinv,
                                                 int* __restrict__ csr, int n, int e) {
    int b = blockIdx.x;
    int p0 = boff[b], p1 = boff[b + 1];
    __shared__ int scnt[TPB];
    __shared__ int sbase[TPB];
    __shared__ int lds[TPB];
    int tid = threadIdx.x;
    scnt[tid] = 0;
    __syncthreads();
    for (int j = p0 + tid; j < p1; j += TPB)
        atomicAdd(&scnt[pairs[j].y & (TPB - 1)], 1);
    __syncthreads();
    int c = scnt[tid];
    lds[tid] = c;
    __syncthreads();
    for (int off = 1; off < TPB; off <<= 1) {
        int x = (tid >= off) ? lds[tid - off] : 0;
        __syncthreads();
        lds[tid] += x;
        __syncthreads();
    }
    int excl = lds[tid] - c;
    sbase[tid] = p0 + excl;
    int node = (b << BSH) + tid;
    if (node < n) {
        rowptr[node] = p0 + excl;
        dinv[node] = rsqrtf(1.0f + (float)c);  // +1 self-loop
    }
    if (b == 0 && tid == 0) rowptr[n] = e;
    __syncthreads();
    for (int j = p0 + tid; j < p1; j += TPB) {
        int2 pr = pairs[j];
        int pos = atomicAdd(&sbase[pr.y & (TPB - 1)], 1);
        csr[pos] = pr.x;
    }
}

// xs[i][k] = half( x[i][k] * dinv[i] )
template <int K>
__global__ __launch_bounds__(TPB) void prescale(const float* __restrict__ x,
                                                const float* __restrict__ dinv,
                                                __half* __restrict__ xs, int n) {
    int idx = blockIdx.x * TPB + threadIdx.x;
    if (idx < n * K) xs[idx] = __float2half(x[idx] * dinv[idx / K]);
}

static __device__ __forceinline__ void acc8(float* a, const h8& v) {
    float2 f;
    f = __half22float2(v.a); a[0] += f.x; a[1] += f.y;
    f = __half22float2(v.b); a[2] += f.x; a[3] += f.y;
    f = __half22float2(v.c); a[4] += f.x; a[5] += f.y;
    f = __half22float2(v.d); a[6] += f.x; a[7] += f.y;
}

static __device__ __forceinline__ void acc4(float* a, const h4& v) {
    float2 f;
    f = __half22float2(v.a); a[0] += f.x; a[1] += f.y;
    f = __half22float2(v.b); a[2] += f.x; a[3] += f.y;
}

// ---- fused layer: agg (fp16 gather -> f32 LDS tile) + dense transform ----
// hs: fp16 [n][K]. Phase A: 16B (8-half) lanes per node (8B for K=4), unroll-8.
// Phase B: out[i][c] = (relu?)( sum_k tile[i][k]*W[k][c] + b[c] ) * (dinv[i]?)
// processed in 32-node sub-blocks to bound the live set (acc[<=8] + wc[16]).
template <int K, int CO, int NODES, bool RELU_OUT, bool SCALE_OUT, bool OUT_HALF>
__global__ __launch_bounds__(TPB) void fused_layer(const __half* __restrict__ hs,
                                                   const int* __restrict__ rowptr,
                                                   const int* __restrict__ csr,
                                                   const float* __restrict__ dinv,
                                                   const float* __restrict__ W,
                                                   const float* __restrict__ bias,
                                                   void* __restrict__ outv, int n) {
    __shared__ float tile[NODES * K];  // f32, max 16 KB (64x64)
    int i0 = blockIdx.x * NODES;

    // ================= phase A: gather =================
    if constexpr (K == 4) {
        static_assert(NODES == TPB, "K=4 path assumes one node per thread");
        const h4* hv = (const h4*)hs;
        int ln = threadIdx.x;
        int i = i0 + ln;
        if (i < n) {
            float a[4];
            {
                h4 v = hv[i];
                float2 f = __half22float2(v.a); a[0] = f.x; a[1] = f.y;
                f = __half22float2(v.b); a[2] = f.x; a[3] = f.y;
            }
            int j = rowptr[i], re = rowptr[i + 1];
            for (; j + 8 <= re; j += 8) {
                h4 v0 = hv[csr[j + 0]], v1 = hv[csr[j + 1]], v2 = hv[csr[j + 2]], v3 = hv[csr[j + 3]];
                h4 v4 = hv[csr[j + 4]], v5 = hv[csr[j + 5]], v6 = hv[csr[j + 6]], v7 = hv[csr[j + 7]];
                acc4(a, v0); acc4(a, v1); acc4(a, v2); acc4(a, v3);
                acc4(a, v4); acc4(a, v5); acc4(a, v6); acc4(a, v7);
            }
            for (; j < re; ++j) acc4(a, hv[csr[j]]);
            float di = dinv[i];
            *(float4*)(tile + ln * 4) =
                make_float4(a[0] * di, a[1] * di, a[2] * di, a[3] * di);
        }
    } else {
        constexpr int L = K / 8;          // 16B lanes per node
        constexpr int NGRP = TPB / L;     // nodes per round
        constexpr int ROUNDS = NODES / NGRP;
        const h8* hv = (const h8*)hs;
        int cl = threadIdx.x % L, grp = threadIdx.x / L;
#pragma unroll 1
        for (int r = 0; r < ROUNDS; ++r) {
            int ln = r * NGRP + grp;
            int i = i0 + ln;
            if (i < n) {
                float a[8];
                {
                    h8 v = hv[(size_t)i * L + cl];
                    float2 f = __half22float2(v.a); a[0] = f.x; a[1] = f.y;
                    f = __half22float2(v.b); a[2] = f.x; a[3] = f.y;
                    f = __half22float2(v.c); a[4] = f.x; a[5] = f.y;
                    f = __half22float2(v.d); a[6] = f.x; a[7] = f.y;
                }
                int j = rowptr[i], re = rowptr[i + 1];
                for (; j + 8 <= re; j += 8) {
                    h8 v0 = hv[(size_t)csr[j + 0] * L + cl], v1 = hv[(size_t)csr[j + 1] * L + cl];
                    h8 v2 = hv[(size_t)csr[j + 2] * L + cl], v3 = hv[(size_t)csr[j + 3] * L + cl];
                    h8 v4 = hv[(size_t)csr[j + 4] * L + cl], v5 = hv[(size_t)csr[j + 5] * L + cl];
                    h8 v6 = hv[(size_t)csr[j + 6] * L + cl], v7 = hv[(size_t)csr[j + 7] * L + cl];
                    acc8(a, v0); acc8(a, v1); acc8(a, v2); acc8(a, v3);
                    acc8(a, v4); acc8(a, v5); acc8(a, v6); acc8(a, v7);
                }
                if (j + 4 <= re) {
                    h8 v0 = hv[(size_t)csr[j + 0] * L + cl], v1 = hv[(size_t)csr[j + 1] * L + cl];
                    h8 v2 = hv[(size_t)csr[j + 2] * L + cl], v3 = hv[(size_t)csr[j + 3] * L + cl];
                    acc8(a, v0); acc8(a, v1); acc8(a, v2); acc8(a, v3);
                    j += 4;
                }
                for (; j < re; ++j) acc8(a, hv[(size_t)csr[j] * L + cl]);
                float di = dinv[i];
                float4* t4 = (float4*)(tile + ln * K + cl * 8);
                t4[0] = make_float4(a[0] * di, a[1] * di, a[2] * di, a[3] * di);
                t4[1] = make_float4(a[4] * di, a[5] * di, a[6] * di, a[7] * di);
            }
        }
    }
    __syncthreads();

    // ================= phase B: dense transform =================
    constexpr int SLOTS = TPB / CO;
    constexpr int HB = (NODES > 32) ? 32 : NODES;  // node sub-block
    constexpr int NPT = HB / SLOTS;                // 8 (L2/L3), 4 (L1)
    constexpr int KT = (K > 16) ? 16 : K;
    int c = threadIdx.x % CO;
    int slot = threadIdx.x / CO;
    float bc = bias[c];

#pragma unroll 1
    for (int hb = 0; hb < NODES; hb += HB) {
        float acc[NPT];
#pragma unroll
        for (int t = 0; t < NPT; ++t) acc[t] = 0.0f;

#pragma unroll 1
        for (int p = 0; p < K; p += KT) {
            float wc[KT];
#pragma unroll
            for (int k = 0; k < KT; ++k) wc[k] = W[(size_t)(p + k) * CO + c];
#pragma unroll
            for (int t = 0; t < NPT; ++t) {
                const float4* row = (const float4*)(tile + (hb + slot * NPT + t) * K + p);
#pragma unroll
                for (int q = 0; q < KT / 4; ++q) {
                    float4 r = row[q];
                    acc[t] = fmaf(r.x, wc[4 * q + 0], acc[t]);
                    acc[t] = fmaf(r.y, wc[4 * q + 1], acc[t]);
                    acc[t] = fmaf(r.z, wc[4 * q + 2], acc[t]);
                    acc[t] = fmaf(r.w, wc[4 * q + 3], acc[t]);
                }
            }
        }
#pragma unroll
        for (int t = 0; t < NPT; ++t) {
            int i = i0 + hb + slot * NPT + t;
            if (i < n) {
                float v = acc[t] + bc;
                if (RELU_OUT) v = fmaxf(v, 0.0f);
                if (SCALE_OUT) v *= dinv[i];
                if (OUT_HALF)
                    ((__half*)outv)[(size_t)i * CO + c] = __float2half(v);
                else
                    ((float*)outv)[(size_t)i * CO + c] = v;
            }
        }
    }
}

extern "C" void kernel_launch(void* const* d_in, const int* in_sizes, int n_in,
                              void* d_out, int out_size, void* d_ws, size_t ws_size,
                              hipStream_t stream) {
    const float* x  = (const float*)d_in[0];
    const int*   ei = (const int*)d_in[1];
    const float* W1 = (const float*)d_in[2];
    const float* b1 = (const float*)d_in[3];
    const float* W2 = (const float*)d_in[4];
    const float* b2 = (const float*)d_in[5];
    const float* W3 = (const float*)d_in[6];
    const float* b3 = (const float*)d_in[7];
    float* out = (float*)d_out;

    const int n = in_sizes[0] / 4;   // 100000
    const int e = in_sizes[1] / 2;   // 1600000
    const int* src = ei;
    const int* dst = ei + e;
    const int nb = cdiv(n, 1 << BSH);  // 391 buckets (NBMAX=512 slots)

    char* ws = (char*)d_ws;
    size_t off = 0;
    auto carve = [&](size_t bytes) {
        char* p = ws + off;
        off = (off + bytes + 255) & ~(size_t)255;
        return p;
    };
    float*  dinv   = (float*) carve((size_t)n * 4);
    int*    rowptr = (int*)   carve((size_t)(n + 1) * 4);
    int*    bhist  = (int*)   carve((size_t)(NBMAX + 1) * 4);
    int*    boff   = (int*)   carve((size_t)(NBMAX + 1) * 4);
    int*    bcur   = (int*)   carve((size_t)(NBMAX + 1) * 4);
    int*    csr    = (int*)   carve((size_t)e * 4);
    int2*   pairs  = (int2*)  carve((size_t)e * 8);        // 12.8 MB, CSR build only
    __half* Ah     = (__half*)carve((size_t)n * 64 * 2);   // h2s fp16
    __half* Bh     = (__half*)carve((size_t)n * 32 * 2);   // h1s fp16
    __half* xs     = (__half*)carve((size_t)n * 4 * 2);    // prescaled x fp16

    const int eblk = cdiv(e, TPB * IPT);  // 196 blocks over edges

    // ---- CSR + norms (LDS-staged multisplit counting sort) ----
    bhist_zero<<<cdiv(NBMAX + 1, TPB), TPB, 0, stream>>>(bhist, NBMAX + 1);
    ms_hist<<<eblk, TPB, 0, stream>>>(dst, bhist, e);
    bscan<<<1, TPB, 0, stream>>>(bhist, boff, bcur);
    ms_scatter<<<eblk, TPB, 0, stream>>>(src, dst, bcur, pairs, e);
    build_csr<<<nb, TPB, 0, stream>>>(pairs, boff, rowptr, dinv, csr, n, e);

    // ---- layer 1: xs = half(x*dinv); fused agg(K=4)+xw(4->32) -> Bh ----
    prescale<4><<<cdiv((long long)n * 4, TPB), TPB, 0, stream>>>(x, dinv, xs, n);
    fused_layer<4, 32, 256, true, true, true><<<cdiv(n, 256), TPB, 0, stream>>>(
        xs, rowptr, csr, dinv, W1, b1, Bh, n);

    // ---- layer 2: fused agg(K=32)+xw(32->64) -> Ah ----
    fused_layer<32, 64, 64, true, true, true><<<cdiv(n, 64), TPB, 0, stream>>>(
        Bh, rowptr, csr, dinv, W2, b2, Ah, n);

    // ---- layer 3: fused agg(K=64)+xw(64->64) -> out (f32) ----
    fused_layer<64, 64, 64, false, false, false><<<cdiv(n, 64), TPB, 0, stream>>>(
        Ah, rowptr, csr, dinv, W3, b3, out, n);
}

// Round 12
// 166.404 us; speedup vs baseline: 4.1456x; 1.0684x over previous
//
#include <hip/hip_runtime.h>
#include <hip/hip_fp16.h>

// 3-layer GCN, pull-mode CSR gather, aggregate-before-transform, fp16 feature
// storage. R12: (1) gather accumulates 4 edges in packed fp16 (__hadd2) then
// flushes to f32 pk-adds -> ~2.3x VALU cut in the per-edge loop that R11 showed
// is the bottleneck (both layers 62us regardless of bytes); (2) 32-node tiles
// (layer2 TPB=128) -> 3125 blocks/layer, ~2x resident waves; (3) CSR pairs
// packed into one int32 (src | local<<24), IPT=16.

#define TPB 256
#define BSH 8                 // 256 nodes per bucket
#define NBMAX 512             // LDS histogram slots (nb = 391 actual)
#define IPT 16                // edges per thread -> 4096 edges per block

static inline int cdiv(long long a, int b) { return (int)((a + b - 1) / b); }

typedef __attribute__((ext_vector_type(2))) float v2f;

struct alignas(16) h8 { __half2 a, b, c, d; };  // 8 halves = 16 B
struct alignas(8)  h4 { __half2 a, b; };        // 4 halves = 8 B

static __device__ __forceinline__ h8 add8(const h8& x, const h8& y) {
    h8 r;
    r.a = __hadd2(x.a, y.a); r.b = __hadd2(x.b, y.b);
    r.c = __hadd2(x.c, y.c); r.d = __hadd2(x.d, y.d);
    return r;
}
static __device__ __forceinline__ void flushA(v2f* A, const h8& s) {
    float2 f;
    f = __half22float2(s.a); { v2f t; t.x = f.x; t.y = f.y; A[0] += t; }
    f = __half22float2(s.b); { v2f t; t.x = f.x; t.y = f.y; A[1] += t; }
    f = __half22float2(s.c); { v2f t; t.x = f.x; t.y = f.y; A[2] += t; }
    f = __half22float2(s.d); { v2f t; t.x = f.x; t.y = f.y; A[3] += t; }
}

__global__ __launch_bounds__(TPB) void bhist_zero(int* __restrict__ bhist, int m) {
    int i = blockIdx.x * TPB + threadIdx.x;
    if (i < m) bhist[i] = 0;
}

__global__ __launch_bounds__(TPB) void ms_hist(const int* __restrict__ dst,
                                               int* __restrict__ bhist, int e) {
    __shared__ int h[NBMAX];
    int tid = threadIdx.x;
    h[tid] = 0; h[tid + TPB] = 0;
    __syncthreads();
    int base = blockIdx.x * (TPB * IPT);
#pragma unroll 8
    for (int k = 0; k < IPT; ++k) {
        int i = base + k * TPB + tid;
        if (i < e) atomicAdd(&h[dst[i] >> BSH], 1);
    }
    __syncthreads();
    int v0 = h[tid], v1 = h[tid + TPB];
    if (v0) atomicAdd(&bhist[tid], v0);
    if (v1) atomicAdd(&bhist[tid + TPB], v1);
}

// single-block exclusive scan of bhist[NBMAX] -> boff/bcur[0..NBMAX]
__global__ __launch_bounds__(TPB) void bscan(const int* __restrict__ bhist,
                                             int* __restrict__ boff,
                                             int* __restrict__ bcur) {
    __shared__ int lds[TPB];
    int tid = threadIdx.x;
    int a = bhist[2 * tid], b = bhist[2 * tid + 1];
    int s = a + b;
    lds[tid] = s;
    __syncthreads();
    for (int off = 1; off < TPB; off <<= 1) {
        int x = (tid >= off) ? lds[tid - off] : 0;
        __syncthreads();
        lds[tid] += x;
        __syncthreads();
    }
    int excl = lds[tid] - s;
    boff[2 * tid] = excl;       bcur[2 * tid] = excl;
    boff[2 * tid + 1] = excl + a; bcur[2 * tid + 1] = excl + a;
    if (tid == TPB - 1) { boff[NBMAX] = lds[TPB - 1]; bcur[NBMAX] = lds[TPB - 1]; }
}

// pairs packed: src (24 bits) | local-dst (8 bits, dst & 255) << 24
__global__ __launch_bounds__(TPB) void ms_scatter(const int* __restrict__ src,
                                                  const int* __restrict__ dst,
                                                  int* __restrict__ bcur,
                                                  int* __restrict__ pairs, int e) {
    __shared__ int h[NBMAX];
    __shared__ int sbase[NBMAX];
    int tid = threadIdx.x;
    h[tid] = 0; h[tid + TPB] = 0;
    __syncthreads();
    int base = blockIdx.x * (TPB * IPT);
#pragma unroll 8
    for (int k = 0; k < IPT; ++k) {
        int i = base + k * TPB + tid;
        if (i < e) atomicAdd(&h[dst[i] >> BSH], 1);
    }
    __syncthreads();
    int v0 = h[tid], v1 = h[tid + TPB];
    if (v0) sbase[tid] = atomicAdd(&bcur[tid], v0);
    if (v1) sbase[tid + TPB] = atomicAdd(&bcur[tid + TPB], v1);
    __syncthreads();
#pragma unroll 8
    for (int k = 0; k < IPT; ++k) {
        int i = base + k * TPB + tid;
        if (i < e) {
            int s = src[i], d = dst[i];
            int pos = atomicAdd(&sbase[d >> BSH], 1);
            pairs[pos] = s | ((d & 255) << 24);
        }
    }
}

// one WG per bucket: histogram -> scan -> rowptr/dinv -> csr placement
__global__ __launch_bounds__(TPB) void build_csr(const int* __restrict__ pairs,
                                                 const int* __restrict__ boff,
                                                 int* __restrict__ rowptr,
                                                 float* __restrict__ dinv,
                                                 int* __restrict__ csr, int n, int e) {
    int b = blockIdx.x;
    int p0 = boff[b], p1 = boff[b + 1];
    __shared__ int scnt[TPB];
    __shared__ int sbase[TPB];
    __shared__ int lds[TPB];
    int tid = threadIdx.x;
    scnt[tid] = 0;
    __syncthreads();
    for (int j = p0 + tid; j < p1; j += TPB)
        atomicAdd(&scnt[((unsigned)pairs[j]) >> 24], 1);
    __syncthreads();
    int c = scnt[tid];
    lds[tid] = c;
    __syncthreads();
    for (int off = 1; off < TPB; off <<= 1) {
        int x = (tid >= off) ? lds[tid - off] : 0;
        __syncthreads();
        lds[tid] += x;
        __syncthreads();
    }
    int excl = lds[tid] - c;
    sbase[tid] = p0 + excl;
    int node = (b << BSH) + tid;
    if (node < n) {
        rowptr[node] = p0 + excl;
        dinv[node] = rsqrtf(1.0f + (float)c);  // +1 self-loop
    }
    if (b == 0 && tid == 0) rowptr[n] = e;
    __syncthreads();
    for (int j = p0 + tid; j < p1; j += TPB) {
        int pr = pairs[j];
        int pos = atomicAdd(&sbase[((unsigned)pr) >> 24], 1);
        csr[pos] = pr & 0xFFFFFF;
    }
}

// xs[i][k] = half( x[i][k] * dinv[i] )
template <int K>
__global__ __launch_bounds__(TPB) void prescale(const float* __restrict__ x,
                                                const float* __restrict__ dinv,
                                                __half* __restrict__ xs, int n) {
    int idx = blockIdx.x * TPB + threadIdx.x;
    if (idx < n * K) xs[idx] = __float2half(x[idx] * dinv[idx / K]);
}

static __device__ __forceinline__ void acc4f(float* a, const h4& v) {
    float2 f;
    f = __half22float2(v.a); a[0] += f.x; a[1] += f.y;
    f = __half22float2(v.b); a[2] += f.x; a[3] += f.y;
}

// ---- fused layer: agg (fp16 gather -> f32 LDS tile) + dense transform ----
// K>=8 gather: 8-half lanes; 4-edge packed-fp16 partial sums flushed to f32 pk.
template <int TPBT, int K, int CO, int NODES, bool RELU_OUT, bool SCALE_OUT, bool OUT_HALF>
__global__ __launch_bounds__(TPBT) void fused_layer(const __half* __restrict__ hs,
                                                    const int* __restrict__ rowptr,
                                                    const int* __restrict__ csr,
                                                    const float* __restrict__ dinv,
                                                    const float* __restrict__ W,
                                                    const float* __restrict__ bias,
                                                    void* __restrict__ outv, int n) {
    __shared__ float tile[NODES * K];
    int i0 = blockIdx.x * NODES;

    // ================= phase A: gather =================
    if constexpr (K == 4) {
        static_assert(NODES == TPBT, "K=4 path: one node per thread");
        const h4* hv = (const h4*)hs;
        int ln = threadIdx.x;
        int i = i0 + ln;
        if (i < n) {
            float a[4] = {0.f, 0.f, 0.f, 0.f};
            acc4f(a, hv[i]);  // self-loop
            int j = rowptr[i], re = rowptr[i + 1];
            for (; j + 8 <= re; j += 8) {
                h4 v0 = hv[csr[j + 0]], v1 = hv[csr[j + 1]], v2 = hv[csr[j + 2]], v3 = hv[csr[j + 3]];
                h4 v4 = hv[csr[j + 4]], v5 = hv[csr[j + 5]], v6 = hv[csr[j + 6]], v7 = hv[csr[j + 7]];
                acc4f(a, v0); acc4f(a, v1); acc4f(a, v2); acc4f(a, v3);
                acc4f(a, v4); acc4f(a, v5); acc4f(a, v6); acc4f(a, v7);
            }
            for (; j < re; ++j) acc4f(a, hv[csr[j]]);
            float di = dinv[i];
            *(float4*)(tile + ln * 4) =
                make_float4(a[0] * di, a[1] * di, a[2] * di, a[3] * di);
        }
    } else {
        constexpr int L = K / 8;             // 16B lanes per node
        constexpr int NGRP = TPBT / L;       // nodes per round
        static_assert(NGRP == NODES, "all threads active in phase A");
        const h8* hv = (const h8*)hs;
        int cl = threadIdx.x % L, grp = threadIdx.x / L;
        int i = i0 + grp;
        if (i < n) {
            v2f A[4];
            A[0] = 0.f; A[1] = 0.f; A[2] = 0.f; A[3] = 0.f;
            flushA(A, hv[(size_t)i * L + cl]);  // self-loop
            int j = rowptr[i], re = rowptr[i + 1];
            for (; j + 8 <= re; j += 8) {
                h8 v0 = hv[(size_t)csr[j + 0] * L + cl], v1 = hv[(size_t)csr[j + 1] * L + cl];
                h8 v2 = hv[(size_t)csr[j + 2] * L + cl], v3 = hv[(size_t)csr[j + 3] * L + cl];
                h8 v4 = hv[(size_t)csr[j + 4] * L + cl], v5 = hv[(size_t)csr[j + 5] * L + cl];
                h8 v6 = hv[(size_t)csr[j + 6] * L + cl], v7 = hv[(size_t)csr[j + 7] * L + cl];
                flushA(A, add8(add8(v0, v1), add8(v2, v3)));  // 4-edge fp16 partial
                flushA(A, add8(add8(v4, v5), add8(v6, v7)));
            }
            if (j + 4 <= re) {
                h8 v0 = hv[(size_t)csr[j + 0] * L + cl], v1 = hv[(size_t)csr[j + 1] * L + cl];
                h8 v2 = hv[(size_t)csr[j + 2] * L + cl], v3 = hv[(size_t)csr[j + 3] * L + cl];
                flushA(A, add8(add8(v0, v1), add8(v2, v3)));
                j += 4;
            }
            for (; j < re; ++j) flushA(A, hv[(size_t)csr[j] * L + cl]);
            float di = dinv[i];
            float4* t4 = (float4*)(tile + grp * K + cl * 8);
            t4[0] = make_float4(A[0].x * di, A[0].y * di, A[1].x * di, A[1].y * di);
            t4[1] = make_float4(A[2].x * di, A[2].y * di, A[3].x * di, A[3].y * di);
        }
    }
    __syncthreads();

    // ================= phase B: dense transform =================
    constexpr int SLOTS = TPBT / CO;
    constexpr int HB = (NODES < SLOTS * 8) ? NODES : SLOTS * 8;  // node sub-block
    constexpr int NPT = HB / SLOTS;                              // <= 8
    constexpr int KT = (K > 16) ? 16 : K;
    int c = threadIdx.x % CO;
    int slot = threadIdx.x / CO;
    float bc = bias[c];

#pragma unroll 1
    for (int hb = 0; hb < NODES; hb += HB) {
        float acc[NPT];
#pragma unroll
        for (int t = 0; t < NPT; ++t) acc[t] = 0.0f;

#pragma unroll 1
        for (int p = 0; p < K; p += KT) {
            float wc[KT];
#pragma unroll
            for (int k = 0; k < KT; ++k) wc[k] = W[(size_t)(p + k) * CO + c];
#pragma unroll
            for (int t = 0; t < NPT; ++t) {
                const float4* row = (const float4*)(tile + (hb + slot * NPT + t) * K + p);
#pragma unroll
                for (int q = 0; q < KT / 4; ++q) {
                    float4 r = row[q];
                    acc[t] = fmaf(r.x, wc[4 * q + 0], acc[t]);
                    acc[t] = fmaf(r.y, wc[4 * q + 1], acc[t]);
                    acc[t] = fmaf(r.z, wc[4 * q + 2], acc[t]);
                    acc[t] = fmaf(r.w, wc[4 * q + 3], acc[t]);
                }
            }
        }
#pragma unroll
        for (int t = 0; t < NPT; ++t) {
            int i = i0 + hb + slot * NPT + t;
            if (i < n) {
                float v = acc[t] + bc;
                if (RELU_OUT) v = fmaxf(v, 0.0f);
                if (SCALE_OUT) v *= dinv[i];
                if (OUT_HALF)
                    ((__half*)outv)[(size_t)i * CO + c] = __float2half(v);
                else
                    ((float*)outv)[(size_t)i * CO + c] = v;
            }
        }
    }
}

extern "C" void kernel_launch(void* const* d_in, const int* in_sizes, int n_in,
                              void* d_out, int out_size, void* d_ws, size_t ws_size,
                              hipStream_t stream) {
    const float* x  = (const float*)d_in[0];
    const int*   ei = (const int*)d_in[1];
    const float* W1 = (const float*)d_in[2];
    const float* b1 = (const float*)d_in[3];
    const float* W2 = (const float*)d_in[4];
    const float* b2 = (const float*)d_in[5];
    const float* W3 = (const float*)d_in[6];
    const float* b3 = (const float*)d_in[7];
    float* out = (float*)d_out;

    const int n = in_sizes[0] / 4;   // 100000
    const int e = in_sizes[1] / 2;   // 1600000
    const int* src = ei;
    const int* dst = ei + e;
    const int nb = cdiv(n, 1 << BSH);  // 391 buckets (NBMAX=512 slots)

    char* ws = (char*)d_ws;
    size_t off = 0;
    auto carve = [&](size_t bytes) {
        char* p = ws + off;
        off = (off + bytes + 255) & ~(size_t)255;
        return p;
    };
    float*  dinv   = (float*) carve((size_t)n * 4);
    int*    rowptr = (int*)   carve((size_t)(n + 1) * 4);
    int*    bhist  = (int*)   carve((size_t)(NBMAX + 1) * 4);
    int*    boff   = (int*)   carve((size_t)(NBMAX + 1) * 4);
    int*    bcur   = (int*)   carve((size_t)(NBMAX + 1) * 4);
    int*    csr    = (int*)   carve((size_t)e * 4);
    int*    pairs  = (int*)   carve((size_t)e * 4);        // packed src|local<<24
    __half* Ah     = (__half*)carve((size_t)n * 64 * 2);   // h2s fp16
    __half* Bh     = (__half*)carve((size_t)n * 32 * 2);   // h1s fp16
    __half* xs     = (__half*)carve((size_t)n * 4 * 2);    // prescaled x fp16

    const int eblk = cdiv(e, TPB * IPT);  // 391 blocks over edges

    // ---- CSR + norms (LDS-staged multisplit counting sort) ----
    bhist_zero<<<cdiv(NBMAX + 1, TPB), TPB, 0, stream>>>(bhist, NBMAX + 1);
    ms_hist<<<eblk, TPB, 0, stream>>>(dst, bhist, e);
    bscan<<<1, TPB, 0, stream>>>(bhist, boff, bcur);
    ms_scatter<<<eblk, TPB, 0, stream>>>(src, dst, bcur, pairs, e);
    build_csr<<<nb, TPB, 0, stream>>>(pairs, boff, rowptr, dinv, csr, n, e);

    // ---- layer 1: xs = half(x*dinv); fused agg(K=4)+xw(4->32) -> Bh ----
    prescale<4><<<cdiv((long long)n * 4, TPB), TPB, 0, stream>>>(x, dinv, xs, n);
    fused_layer<256, 4, 32, 256, true, true, true><<<cdiv(n, 256), 256, 0, stream>>>(
        xs, rowptr, csr, dinv, W1, b1, Bh, n);

    // ---- layer 2: fused agg(K=32)+xw(32->64) -> Ah  (TPB=128, 32-node tiles) ----
    fused_layer<128, 32, 64, 32, true, true, true><<<cdiv(n, 32), 128, 0, stream>>>(
        Bh, rowptr, csr, dinv, W2, b2, Ah, n);

    // ---- layer 3: fused agg(K=64)+xw(64->64) -> out (f32, 32-node tiles) ----
    fused_layer<256, 64, 64, 32, false, false, false><<<cdiv(n, 32), 256, 0, stream>>>(
        Ah, rowptr, csr, dinv, W3, b3, out, n);
}